// Round 1
// baseline (958.978 us; speedup 1.0000x reference)
//
#include <hip/hip_runtime.h>
#include <stdint.h>

typedef __attribute__((ext_vector_type(8))) short bf16x8;
typedef __attribute__((ext_vector_type(4))) float f32x4;
typedef unsigned short u16;
typedef unsigned int u32;

#define NLVL 16
#define NNODE 16384
#define MPL 1024
#define DIN 1024
#define DH 256

__device__ __forceinline__ u16 f2bf(float f) {
  u32 u = __builtin_bit_cast(u32, f);
  u += 0x7FFFu + ((u >> 16) & 1u);
  return (u16)(u >> 16);
}
__device__ __forceinline__ float b2f(u16 h) {
  u32 u = ((u32)h) << 16;
  return __builtin_bit_cast(float, u);
}
__device__ __forceinline__ float fsig(float x) {
  return __builtin_amdgcn_rcpf(1.0f + __expf(-x));
}
__device__ __forceinline__ float ftanh(float x) {
  return 1.0f - 2.0f * __builtin_amdgcn_rcpf(__expf(2.0f * x) + 1.0f);
}

__device__ __forceinline__ void async_copy16(const void* g, void* lds) {
  __builtin_amdgcn_global_load_lds((const __attribute__((address_space(1))) void*)g,
                                   (__attribute__((address_space(3))) void*)lds, 16, 0, 0);
}

// ---------------- conversion kernels ----------------
__global__ __launch_bounds__(256) void k_cvt_x(const float* __restrict__ x,
                                               u16* __restrict__ xb) {
  size_t i = (size_t)blockIdx.x * 256 + threadIdx.x;  // one thread = 8 elems
  const float4* p = (const float4*)x + i * 2;
  float4 v0 = p[0], v1 = p[1];
  union { u16 s[8]; uint4 v; } o;
  o.s[0] = f2bf(v0.x); o.s[1] = f2bf(v0.y); o.s[2] = f2bf(v0.z); o.s[3] = f2bf(v0.w);
  o.s[4] = f2bf(v1.x); o.s[5] = f2bf(v1.y); o.s[6] = f2bf(v1.z); o.s[7] = f2bf(v1.w);
  *((uint4*)(xb + i * 8)) = o.v;
}

__global__ __launch_bounds__(256) void k_cvt_w(
    const float* __restrict__ Wioux, const float* __restrict__ Wfx,
    const float* __restrict__ Wiouh, const float* __restrict__ Wfh,
    const float* __restrict__ bioux, const float* __restrict__ bfx,
    const float* __restrict__ biouh, const float* __restrict__ bfh,
    u16* __restrict__ Wxb, u16* __restrict__ Whb,
    float* __restrict__ b1, float* __restrict__ b2) {
  int t = blockIdx.x * 256 + threadIdx.x;
  if (t < 131072) {  // Wxb [1024][1024] bf16
    int idx = t * 8;
    int row = idx >> 10, col = idx & 1023;
    const float* src = (row < 768) ? (Wioux + (size_t)row * 1024 + col)
                                   : (Wfx + (size_t)(row - 768) * 1024 + col);
    union { u16 s[8]; uint4 v; } o;
#pragma unroll
    for (int j = 0; j < 8; ++j) o.s[j] = f2bf(src[j]);
    *((uint4*)(Wxb + idx)) = o.v;
  } else if (t < 163840) {  // Whb [1024][256] bf16
    int idx = (t - 131072) * 8;
    int row = idx >> 8, col = idx & 255;
    const float* src = (row < 768) ? (Wiouh + (size_t)row * 256 + col)
                                   : (Wfh + (size_t)(row - 768) * 256 + col);
    union { u16 s[8]; uint4 v; } o;
#pragma unroll
    for (int j = 0; j < 8; ++j) o.s[j] = f2bf(src[j]);
    *((uint4*)(Whb + idx)) = o.v;
  } else if (t < 164096) {  // biases
    int idx = (t - 163840) * 8;
#pragma unroll
    for (int j = 0; j < 8; ++j) {
      int i = idx + j;
      if (i < 1024) b1[i] = (i < 768) ? bioux[i] : bfx[i - 768];
      else { int k = i - 1024; b2[k] = (k < 768) ? biouh[k] : bfh[k - 768]; }
    }
  }
}

// ---------------- phase 1: fused gate-preact GEMM ----------------
// gx[16384][1024] = xb[16384][1024] @ Wxb[1024][1024]^T + bias1
__device__ __forceinline__ int swz2(int row) { return (row & 3) ^ ((row >> 2) & 3); }

__global__ __launch_bounds__(256) void k_gemm1(const u16* __restrict__ xb,
                                               const u16* __restrict__ Wxb,
                                               const float* __restrict__ b1,
                                               float* __restrict__ gx) {
  __shared__ __align__(16) u16 As[2][4096];  // [128][32] bf16, chunk-swizzled
  __shared__ __align__(16) u16 Bs[2][4096];
  const int tid = threadIdx.x, w = tid >> 6, l = tid & 63;
  const int tM = blockIdx.y * 128, tN = blockIdx.x * 128;
  const int wm = w >> 1, wn = w & 1;

  f32x4 acc[4][4];
#pragma unroll
  for (int mt = 0; mt < 4; ++mt)
#pragma unroll
    for (int nt = 0; nt < 4; ++nt) acc[mt][nt] = (f32x4){0.f, 0.f, 0.f, 0.f};

  auto stage = [&](int buf, int t) {
    int k0 = t * 32;
#pragma unroll
    for (int i = 0; i < 2; ++i) {
      int seg = w * 2 + i;
      int row = seg * 16 + (l >> 2);
      int qg = (l & 3) ^ swz2(row);
      async_copy16(xb + (size_t)(tM + row) * 1024 + k0 + qg * 8, &As[buf][seg * 512]);
      async_copy16(Wxb + (size_t)(tN + row) * 1024 + k0 + qg * 8, &Bs[buf][seg * 512]);
    }
  };

  auto compute = [&](int buf) {
    bf16x8 a[4], b[4];
#pragma unroll
    for (int mt = 0; mt < 4; ++mt) {
      int row = wm * 64 + mt * 16 + (l & 15);
      int cs = (l >> 4) ^ swz2(row);
      a[mt] = *(const bf16x8*)&As[buf][row * 32 + cs * 8];
    }
#pragma unroll
    for (int nt = 0; nt < 4; ++nt) {
      int row = wn * 64 + nt * 16 + (l & 15);
      int cs = (l >> 4) ^ swz2(row);
      b[nt] = *(const bf16x8*)&Bs[buf][row * 32 + cs * 8];
    }
#pragma unroll
    for (int mt = 0; mt < 4; ++mt)
#pragma unroll
      for (int nt = 0; nt < 4; ++nt)
        acc[mt][nt] = __builtin_amdgcn_mfma_f32_16x16x32_bf16(a[mt], b[nt], acc[mt][nt], 0, 0, 0);
  };

  stage(0, 0);
  __syncthreads();
  int buf = 0;
  for (int t = 0; t < 32; ++t) {
    if (t + 1 < 32) stage(buf ^ 1, t + 1);
    compute(buf);
    __syncthreads();
    buf ^= 1;
  }

#pragma unroll
  for (int mt = 0; mt < 4; ++mt)
#pragma unroll
    for (int nt = 0; nt < 4; ++nt) {
      int col = tN + wn * 64 + nt * 16 + (l & 15);
      float bias = b1[col];
      int rbase = tM + wm * 64 + mt * 16 + (l >> 4) * 4;
#pragma unroll
      for (int r = 0; r < 4; ++r)
        gx[(size_t)(rbase + r) * 1024 + col] = acc[mt][nt][r] + bias;
    }
}

// ---------------- phase 2: per-level fused TreeLSTM step ----------------
// 64 blocks x 16 nodes. LDS: hch[64][256] bf16 swz, hsum[16][256] bf16 swz,
// iouA[16][768] f32 (activated i,o,u).
__global__ __launch_bounds__(256) void k_level(
    const int* __restrict__ children, const float* __restrict__ gx,
    const u16* __restrict__ Whb, const float* __restrict__ b2,
    u16* __restrict__ hb, float* __restrict__ cb,
    float* __restrict__ hout, int level) {
  __shared__ int ch[64];
  __shared__ __align__(16) u16 hch[64 * 256];
  __shared__ __align__(16) u16 hsum[16 * 256];
  __shared__ float iouA[16 * 768];
  const int tid = threadIdx.x, w = tid >> 6, l = tid & 63;
  const int node0 = level * 1024 + blockIdx.x * 16;

  if (tid < 64) ch[tid] = children[node0 * 4 + tid];
  __syncthreads();

  // gather child h rows (bf16), zero for absent children; swizzled store
#pragma unroll
  for (int it = 0; it < 8; ++it) {
    int id = tid + it * 256;
    int row = id >> 5, q = id & 31;
    int child = ch[row];
    uint4 v = make_uint4(0u, 0u, 0u, 0u);
    if (child >= 0) v = *(const uint4*)(hb + (size_t)child * 256 + q * 8);
    *(uint4*)&hch[row * 256 + ((q ^ (row & 7)) * 8)] = v;
  }
  __syncthreads();

  // hsum (f32 accumulate over the 4 children, stored bf16 swizzled)
#pragma unroll
  for (int it = 0; it < 2; ++it) {
    int id = tid + it * 256;
    int row = id >> 5, q = id & 31;
    float s[8] = {0.f, 0.f, 0.f, 0.f, 0.f, 0.f, 0.f, 0.f};
#pragma unroll
    for (int k = 0; k < 4; ++k) {
      int hr = row * 4 + k;
      bf16x8 v = *(const bf16x8*)&hch[hr * 256 + ((q ^ (hr & 7)) * 8)];
#pragma unroll
      for (int j = 0; j < 8; ++j) s[j] += b2f((u16)v[j]);
    }
    union { u16 us[8]; uint4 v4; } o;
#pragma unroll
    for (int j = 0; j < 8; ++j) o.us[j] = f2bf(s[j]);
    *(uint4*)&hsum[row * 256 + ((q ^ (row & 7)) * 8)] = o.v4;
  }
  __syncthreads();

  // GEMM1: iou = hsum[16][256] @ Wiouh^T ; wave w covers cols [w*192, w*192+192)
  bf16x8 a1[8];
  {
    int arow = l & 15;
#pragma unroll
    for (int ks = 0; ks < 8; ++ks) {
      int chunk = ks * 4 + (l >> 4);
      a1[ks] = *(const bf16x8*)&hsum[arow * 256 + ((chunk ^ (arow & 7)) * 8)];
    }
  }
#pragma unroll 1
  for (int nt = 0; nt < 12; ++nt) {
    int colg = w * 192 + nt * 16 + (l & 15);
    const u16* bp = Whb + (size_t)colg * 256 + (l >> 4) * 8;
    f32x4 acc = (f32x4){0.f, 0.f, 0.f, 0.f};
#pragma unroll
    for (int ks = 0; ks < 8; ++ks) {
      bf16x8 bfr = *(const bf16x8*)(bp + ks * 32);
      acc = __builtin_amdgcn_mfma_f32_16x16x32_bf16(a1[ks], bfr, acc, 0, 0, 0);
    }
    float bias = b2[colg];
#pragma unroll
    for (int r = 0; r < 4; ++r) {
      int nodeL = (l >> 4) * 4 + r;
      float v = acc[r] + gx[(size_t)(node0 + nodeL) * 1024 + colg] + bias;
      iouA[nodeL * 768 + colg] = (colg < 512) ? fsig(v) : ftanh(v);
    }
  }
  __syncthreads();

  // GEMM2 (per-child forget gates) + combine. Wave w: hch rows [w*16, w*16+16)
  bf16x8 a2[8];
  {
    int arow = w * 16 + (l & 15);
#pragma unroll
    for (int ks = 0; ks < 8; ++ks) {
      int chunk = ks * 4 + (l >> 4);
      a2[ks] = *(const bf16x8*)&hch[arow * 256 + ((chunk ^ (arow & 7)) * 8)];
    }
  }
  const int nodeL = w * 4 + (l >> 4);
  const int node = node0 + nodeL;
#pragma unroll 1
  for (int nt = 0; nt < 16; ++nt) {
    int col = nt * 16 + (l & 15);
    const u16* bp = Whb + (size_t)(768 + col) * 256 + (l >> 4) * 8;
    f32x4 acc = (f32x4){0.f, 0.f, 0.f, 0.f};
#pragma unroll
    for (int ks = 0; ks < 8; ++ks) {
      bf16x8 bfr = *(const bf16x8*)(bp + ks * 32);
      acc = __builtin_amdgcn_mfma_f32_16x16x32_bf16(a2[ks], bfr, acc, 0, 0, 0);
    }
    float fx = gx[(size_t)node * 1024 + 768 + col] + b2[768 + col];
    float fcsum = 0.f;
#pragma unroll
    for (int r = 0; r < 4; ++r) {
      int child = ch[nodeL * 4 + r];
      if (child >= 0) {
        float cch = cb[(size_t)child * 256 + col];
        fcsum += fsig(fx + acc[r]) * cch;
      }
    }
    float ig = iouA[nodeL * 768 + col];
    float og = iouA[nodeL * 768 + 256 + col];
    float ug = iouA[nodeL * 768 + 512 + col];
    float cnew = ig * ug + fcsum;
    float hnew = og * ftanh(cnew);
    cb[(size_t)node * 256 + col] = cnew;
    hout[(size_t)node * 256 + col] = hnew;
    hb[(size_t)node * 256 + col] = f2bf(hnew);
  }
}

// ---------------- launch ----------------
extern "C" void kernel_launch(void* const* d_in, const int* in_sizes, int n_in,
                              void* d_out, int out_size, void* d_ws, size_t ws_size,
                              hipStream_t stream) {
  const float* x = (const float*)d_in[0];
  const int* children = (const int*)d_in[1];
  const float* Wioux = (const float*)d_in[2];
  const float* bioux = (const float*)d_in[3];
  const float* Wiouh = (const float*)d_in[4];
  const float* biouh = (const float*)d_in[5];
  const float* Wfx = (const float*)d_in[6];
  const float* bfx = (const float*)d_in[7];
  const float* Wfh = (const float*)d_in[8];
  const float* bfh = (const float*)d_in[9];

  char* ws = (char*)d_ws;
  u16* xb = (u16*)(ws + 0);              // 33,554,432 B
  float* gx = (float*)(ws + 33554432);   // 67,108,864 B
  u16* hb = (u16*)(ws + 100663296);      //  8,388,608 B
  float* cb = (float*)(ws + 109051904);  // 16,777,216 B
  u16* Wxb = (u16*)(ws + 125829120);     //  2,097,152 B
  u16* Whb = (u16*)(ws + 127926272);     //    524,288 B
  float* b1 = (float*)(ws + 128450560);  //      4,096 B
  float* b2 = (float*)(ws + 128454656);  //      4,096 B
  float* hout = (float*)d_out;

  k_cvt_x<<<8192, 256, 0, stream>>>(x, xb);
  k_cvt_w<<<641, 256, 0, stream>>>(Wioux, Wfx, Wiouh, Wfh, bioux, bfx, biouh, bfh,
                                   Wxb, Whb, b1, b2);
  k_gemm1<<<dim3(8, 128), 256, 0, stream>>>(xb, Wxb, b1, gx);
  for (int lvl = 0; lvl < NLVL; ++lvl)
    k_level<<<64, 256, 0, stream>>>(children, gx, Whb, b2, hb, cb, hout, lvl);
}

// Round 2
// 355.433 us; speedup vs baseline: 2.6981x; 2.6981x over previous
//
#include <hip/hip_runtime.h>
#include <stdint.h>

typedef __attribute__((ext_vector_type(8))) short bf16x8;
typedef __attribute__((ext_vector_type(4))) float f32x4;
typedef unsigned short u16;
typedef unsigned int u32;

#define NLVL 16
#define NNODE 16384
#define MPL 1024
#define DIN 1024
#define DH 256

__device__ __forceinline__ u16 f2bf(float f) {
  u32 u = __builtin_bit_cast(u32, f);
  u += 0x7FFFu + ((u >> 16) & 1u);
  return (u16)(u >> 16);
}
__device__ __forceinline__ float b2f(u16 h) {
  u32 u = ((u32)h) << 16;
  return __builtin_bit_cast(float, u);
}
__device__ __forceinline__ float fsig(float x) {
  return __builtin_amdgcn_rcpf(1.0f + __expf(-x));
}
__device__ __forceinline__ float ftanh(float x) {
  return 1.0f - 2.0f * __builtin_amdgcn_rcpf(__expf(2.0f * x) + 1.0f);
}

__device__ __forceinline__ void async_copy16(const void* g, void* lds) {
  __builtin_amdgcn_global_load_lds((const __attribute__((address_space(1))) void*)g,
                                   (__attribute__((address_space(3))) void*)lds, 16, 0, 0);
}

// ---------------- conversion kernels ----------------
__global__ __launch_bounds__(256) void k_cvt_x(const float* __restrict__ x,
                                               u16* __restrict__ xb) {
  size_t i = (size_t)blockIdx.x * 256 + threadIdx.x;  // one thread = 8 elems
  const float4* p = (const float4*)x + i * 2;
  float4 v0 = p[0], v1 = p[1];
  union { u16 s[8]; uint4 v; } o;
  o.s[0] = f2bf(v0.x); o.s[1] = f2bf(v0.y); o.s[2] = f2bf(v0.z); o.s[3] = f2bf(v0.w);
  o.s[4] = f2bf(v1.x); o.s[5] = f2bf(v1.y); o.s[6] = f2bf(v1.z); o.s[7] = f2bf(v1.w);
  *((uint4*)(xb + i * 8)) = o.v;
}

__global__ __launch_bounds__(256) void k_cvt_w(
    const float* __restrict__ Wioux, const float* __restrict__ Wfx,
    const float* __restrict__ Wiouh, const float* __restrict__ Wfh,
    const float* __restrict__ bioux, const float* __restrict__ bfx,
    const float* __restrict__ biouh, const float* __restrict__ bfh,
    u16* __restrict__ Wxb, u16* __restrict__ Whb,
    float* __restrict__ b1, float* __restrict__ b2) {
  int t = blockIdx.x * 256 + threadIdx.x;
  if (t < 131072) {  // Wxb [1024][1024] bf16
    int idx = t * 8;
    int row = idx >> 10, col = idx & 1023;
    const float* src = (row < 768) ? (Wioux + (size_t)row * 1024 + col)
                                   : (Wfx + (size_t)(row - 768) * 1024 + col);
    union { u16 s[8]; uint4 v; } o;
#pragma unroll
    for (int j = 0; j < 8; ++j) o.s[j] = f2bf(src[j]);
    *((uint4*)(Wxb + idx)) = o.v;
  } else if (t < 163840) {  // Whb [1024][256] bf16
    int idx = (t - 131072) * 8;
    int row = idx >> 8, col = idx & 255;
    const float* src = (row < 768) ? (Wiouh + (size_t)row * 256 + col)
                                   : (Wfh + (size_t)(row - 768) * 256 + col);
    union { u16 s[8]; uint4 v; } o;
#pragma unroll
    for (int j = 0; j < 8; ++j) o.s[j] = f2bf(src[j]);
    *((uint4*)(Whb + idx)) = o.v;
  } else if (t < 164096) {  // biases
    int idx = (t - 163840) * 8;
#pragma unroll
    for (int j = 0; j < 8; ++j) {
      int i = idx + j;
      if (i < 1024) b1[i] = (i < 768) ? bioux[i] : bfx[i - 768];
      else { int k = i - 1024; b2[k] = (k < 768) ? biouh[k] : bfh[k - 768]; }
    }
  }
}

// ---------------- phase 1: fused gate-preact GEMM ----------------
// gx[16384][1024] = xb[16384][1024] @ Wxb[1024][1024]^T + bias1
__device__ __forceinline__ int swz2(int row) { return (row & 3) ^ ((row >> 2) & 3); }

__global__ __launch_bounds__(256) void k_gemm1(const u16* __restrict__ xb,
                                               const u16* __restrict__ Wxb,
                                               const float* __restrict__ b1,
                                               float* __restrict__ gx) {
  __shared__ __align__(16) u16 As[2][4096];  // [128][32] bf16, chunk-swizzled
  __shared__ __align__(16) u16 Bs[2][4096];
  const int tid = threadIdx.x, w = tid >> 6, l = tid & 63;
  const int tM = blockIdx.y * 128, tN = blockIdx.x * 128;
  const int wm = w >> 1, wn = w & 1;

  f32x4 acc[4][4];
#pragma unroll
  for (int mt = 0; mt < 4; ++mt)
#pragma unroll
    for (int nt = 0; nt < 4; ++nt) acc[mt][nt] = (f32x4){0.f, 0.f, 0.f, 0.f};

  auto stage = [&](int buf, int t) {
    int k0 = t * 32;
#pragma unroll
    for (int i = 0; i < 2; ++i) {
      int seg = w * 2 + i;
      int row = seg * 16 + (l >> 2);
      int qg = (l & 3) ^ swz2(row);
      async_copy16(xb + (size_t)(tM + row) * 1024 + k0 + qg * 8, &As[buf][seg * 512]);
      async_copy16(Wxb + (size_t)(tN + row) * 1024 + k0 + qg * 8, &Bs[buf][seg * 512]);
    }
  };

  auto compute = [&](int buf) {
    bf16x8 a[4], b[4];
#pragma unroll
    for (int mt = 0; mt < 4; ++mt) {
      int row = wm * 64 + mt * 16 + (l & 15);
      int cs = (l >> 4) ^ swz2(row);
      a[mt] = *(const bf16x8*)&As[buf][row * 32 + cs * 8];
    }
#pragma unroll
    for (int nt = 0; nt < 4; ++nt) {
      int row = wn * 64 + nt * 16 + (l & 15);
      int cs = (l >> 4) ^ swz2(row);
      b[nt] = *(const bf16x8*)&Bs[buf][row * 32 + cs * 8];
    }
#pragma unroll
    for (int mt = 0; mt < 4; ++mt)
#pragma unroll
      for (int nt = 0; nt < 4; ++nt)
        acc[mt][nt] = __builtin_amdgcn_mfma_f32_16x16x32_bf16(a[mt], b[nt], acc[mt][nt], 0, 0, 0);
  };

  stage(0, 0);
  __syncthreads();
  int buf = 0;
  for (int t = 0; t < 32; ++t) {
    if (t + 1 < 32) stage(buf ^ 1, t + 1);
    compute(buf);
    __syncthreads();
    buf ^= 1;
  }

#pragma unroll
  for (int mt = 0; mt < 4; ++mt)
#pragma unroll
    for (int nt = 0; nt < 4; ++nt) {
      int col = tN + wn * 64 + nt * 16 + (l & 15);
      float bias = b1[col];
      int rbase = tM + wm * 64 + mt * 16 + (l >> 4) * 4;
#pragma unroll
      for (int r = 0; r < 4; ++r)
        gx[(size_t)(rbase + r) * 1024 + col] = acc[mt][nt][r] + bias;
    }
}

// ---------------- phase 2: per-level fused TreeLSTM step ----------------
// Grid: dim3(64, 4) — 64 node-tiles (16 nodes) x 4 hidden-col groups (64 h each).
// Block covers iou cols {s*256 + g*64 .. +64, s=0..2} and f cols {g*64 .. +64}.
__global__ __launch_bounds__(256) void k_level(
    const int* __restrict__ children, const float* __restrict__ gx,
    const u16* __restrict__ Whb, const float* __restrict__ b2,
    u16* __restrict__ hb, float* __restrict__ cb,
    float* __restrict__ hout, int level) {
  __shared__ int ch[64];
  __shared__ __align__(16) u16 hch[64 * 256];   // child rows, swizzled
  __shared__ __align__(16) u16 hsum[16 * 256];  // child-sum rows, swizzled
  __shared__ float iouA[16 * 196];              // activated i,o,u (3x64, pad 196)
  const int tid = threadIdx.x, w = tid >> 6, l = tid & 63;
  const int node0 = level * 1024 + blockIdx.x * 16;
  const int h0 = blockIdx.y * 64;  // hidden-col range [h0, h0+64)

  if (tid < 64) ch[tid] = children[node0 * 4 + tid];
  __syncthreads();

  // gather child h rows (bf16), zero for absent children; swizzled store
#pragma unroll
  for (int it = 0; it < 8; ++it) {
    int id = tid + it * 256;
    int row = id >> 5, q = id & 31;
    int child = ch[row];
    uint4 v = make_uint4(0u, 0u, 0u, 0u);
    if (child >= 0) v = *(const uint4*)(hb + (size_t)child * 256 + q * 8);
    *(uint4*)&hch[row * 256 + ((q ^ (row & 7)) * 8)] = v;
  }
  __syncthreads();

  // hsum: f32 accumulate over 4 children, stored bf16 swizzled (16 rows x 32 chunks)
#pragma unroll
  for (int it = 0; it < 2; ++it) {
    int id = tid + it * 256;
    int row = id >> 5, q = id & 31;
    float s[8] = {0.f, 0.f, 0.f, 0.f, 0.f, 0.f, 0.f, 0.f};
#pragma unroll
    for (int k = 0; k < 4; ++k) {
      int hr = row * 4 + k;
      bf16x8 v = *(const bf16x8*)&hch[hr * 256 + ((q ^ (hr & 7)) * 8)];
#pragma unroll
      for (int j = 0; j < 8; ++j) s[j] += b2f((u16)v[j]);
    }
    union { u16 us[8]; uint4 v4; } o;
#pragma unroll
    for (int j = 0; j < 8; ++j) o.us[j] = f2bf(s[j]);
    *(uint4*)&hsum[row * 256 + ((q ^ (row & 7)) * 8)] = o.v4;
  }
  __syncthreads();

  // GEMM1: iou tiles. 12 tiles (3 strips x 4 subtiles of 16 cols), 3 per wave.
  bf16x8 a1[8];
  {
    int arow = l & 15;
#pragma unroll
    for (int ks = 0; ks < 8; ++ks) {
      int chunk = ks * 4 + (l >> 4);
      a1[ks] = *(const bf16x8*)&hsum[arow * 256 + ((chunk ^ (arow & 7)) * 8)];
    }
  }
#pragma unroll
  for (int i = 0; i < 3; ++i) {
    int tt = w * 3 + i;
    int s = tt >> 2, t = tt & 3;
    int colg = s * 256 + h0 + t * 16 + (l & 15);
    const u16* bp = Whb + (size_t)colg * 256 + (l >> 4) * 8;
    f32x4 acc = (f32x4){0.f, 0.f, 0.f, 0.f};
#pragma unroll
    for (int ks = 0; ks < 8; ++ks) {
      bf16x8 bfr = *(const bf16x8*)(bp + ks * 32);
      acc = __builtin_amdgcn_mfma_f32_16x16x32_bf16(a1[ks], bfr, acc, 0, 0, 0);
    }
    float bias = b2[colg];
#pragma unroll
    for (int r = 0; r < 4; ++r) {
      int nodeL = (l >> 4) * 4 + r;
      float v = acc[r] + gx[(size_t)(node0 + nodeL) * 1024 + colg] + bias;
      iouA[nodeL * 196 + s * 64 + t * 16 + (l & 15)] = (s < 2) ? fsig(v) : ftanh(v);
    }
  }
  __syncthreads();

  // GEMM2 (per-child forget gates) + combine. Wave w: child rows [w*16, w*16+16).
  bf16x8 a2[8];
  {
    int arow = w * 16 + (l & 15);
#pragma unroll
    for (int ks = 0; ks < 8; ++ks) {
      int chunk = ks * 4 + (l >> 4);
      a2[ks] = *(const bf16x8*)&hch[arow * 256 + ((chunk ^ (arow & 7)) * 8)];
    }
  }
  const int nodeL = w * 4 + (l >> 4);
  const int node = node0 + nodeL;
#pragma unroll
  for (int nt = 0; nt < 4; ++nt) {
    int hl = nt * 16 + (l & 15);  // local h 0..63
    int hcol = h0 + hl;           // global hidden col
    const u16* bp = Whb + (size_t)(768 + hcol) * 256 + (l >> 4) * 8;
    f32x4 acc = (f32x4){0.f, 0.f, 0.f, 0.f};
#pragma unroll
    for (int ks = 0; ks < 8; ++ks) {
      bf16x8 bfr = *(const bf16x8*)(bp + ks * 32);
      acc = __builtin_amdgcn_mfma_f32_16x16x32_bf16(a2[ks], bfr, acc, 0, 0, 0);
    }
    float fx = gx[(size_t)node * 1024 + 768 + hcol] + b2[768 + hcol];
    float fcsum = 0.f;
#pragma unroll
    for (int r = 0; r < 4; ++r) {
      int child = ch[nodeL * 4 + r];
      if (child >= 0) {
        float cch = cb[(size_t)child * 256 + hcol];
        fcsum += fsig(fx + acc[r]) * cch;
      }
    }
    float ig = iouA[nodeL * 196 + hl];
    float og = iouA[nodeL * 196 + 64 + hl];
    float ug = iouA[nodeL * 196 + 128 + hl];
    float cnew = ig * ug + fcsum;
    float hnew = og * ftanh(cnew);
    cb[(size_t)node * 256 + hcol] = cnew;
    hout[(size_t)node * 256 + hcol] = hnew;
    hb[(size_t)node * 256 + hcol] = f2bf(hnew);
  }
}

// ---------------- launch ----------------
extern "C" void kernel_launch(void* const* d_in, const int* in_sizes, int n_in,
                              void* d_out, int out_size, void* d_ws, size_t ws_size,
                              hipStream_t stream) {
  const float* x = (const float*)d_in[0];
  const int* children = (const int*)d_in[1];
  const float* Wioux = (const float*)d_in[2];
  const float* bioux = (const float*)d_in[3];
  const float* Wiouh = (const float*)d_in[4];
  const float* biouh = (const float*)d_in[5];
  const float* Wfx = (const float*)d_in[6];
  const float* bfx = (const float*)d_in[7];
  const float* Wfh = (const float*)d_in[8];
  const float* bfh = (const float*)d_in[9];

  char* ws = (char*)d_ws;
  u16* xb = (u16*)(ws + 0);              // 33,554,432 B
  float* gx = (float*)(ws + 33554432);   // 67,108,864 B
  u16* hb = (u16*)(ws + 100663296);      //  8,388,608 B
  float* cb = (float*)(ws + 109051904);  // 16,777,216 B
  u16* Wxb = (u16*)(ws + 125829120);     //  2,097,152 B
  u16* Whb = (u16*)(ws + 127926272);     //    524,288 B
  float* b1 = (float*)(ws + 128450560);  //      4,096 B
  float* b2 = (float*)(ws + 128454656);  //      4,096 B
  float* hout = (float*)d_out;

  k_cvt_x<<<8192, 256, 0, stream>>>(x, xb);
  k_cvt_w<<<641, 256, 0, stream>>>(Wioux, Wfx, Wiouh, Wfh, bioux, bfx, biouh, bfh,
                                   Wxb, Whb, b1, b2);
  k_gemm1<<<dim3(8, 128), 256, 0, stream>>>(xb, Wxb, b1, gx);
  for (int lvl = 0; lvl < NLVL; ++lvl)
    k_level<<<dim3(64, 4), 256, 0, stream>>>(children, gx, Whb, b2, hb, cb, hout, lvl);
}